// Round 5
// baseline (560.216 us; speedup 1.0000x reference)
//
#include <hip/hip_runtime.h>

typedef unsigned short u16;
typedef unsigned int   u32;
typedef __bf16 bfx8 __attribute__((ext_vector_type(8)));
typedef float  fx4  __attribute__((ext_vector_type(4)));

__device__ __forceinline__ u16 f2b(float f) {
    union { float f; u32 i; } v; v.f = f;
    u32 r = (v.i + 0x7fffu + ((v.i >> 16) & 1u)) >> 16;
    return (u16)r;
}
__device__ __forceinline__ u32 pk(float a, float b) {
    return (u32)f2b(a) | ((u32)f2b(b) << 16);
}
__device__ __forceinline__ float gelu(float x) {
    float u = 0.7978845608028654f * x * (1.0f + 0.044715f * x * x);
    float e = __expf(2.0f * u);
    float t = 1.0f - 2.0f / (e + 1.0f);   // tanh(u)
    return 0.5f * x * (1.0f + t);
}

__device__ __forceinline__ void gl2lds16(const u16* g, u16* l) {
    __builtin_amdgcn_global_load_lds(
        (const __attribute__((address_space(1))) u32*)(const void*)g,
        (__attribute__((address_space(3))) u32*)(void*)l, 16, 0, 0);
}

// partitioned row r (window-major) -> token index in [0,32768), with roll shift
__device__ __forceinline__ int map_token(int r, int shift) {
    int win = r >> 6, n = r & 63;
    int wh = win >> 6, ww = (win >> 3) & 7, wt = win & 7;
    int h = wh * 4 + (n >> 4);
    int w = ww * 4 + ((n >> 2) & 3);
    int t = wt * 4 + (n & 3);
    h = (h + shift) & 31; w = (w + shift) & 31; t = (t + shift) & 31;
    return (h << 10) | (w << 5) | t;
}

// ---------- batched fp32 -> bf16 weight conversion ----------
struct CvtArgs { const float* src[8]; int cum[9]; };
__global__ __launch_bounds__(256) void cvt_kernel(CvtArgs a, u16* __restrict__ dst) {
    int g = (blockIdx.x * 256 + threadIdx.x) * 4;
    int t = 0;
    #pragma unroll
    for (int i = 1; i < 8; i++) t += (g >= a.cum[i]);
    int local = g - a.cum[t];
    float4 f = *(const float4*)(a.src[t] + local);
    uint2 o; o.x = pk(f.x, f.y); o.y = pk(f.z, f.w);
    *(uint2*)(dst + g) = o;
}

// ---------- attention bias+mask table: slab 0..7 = unshifted heads; 8+cls*8+head = shifted ----------
__global__ __launch_bounds__(64) void bias_kernel(const float* __restrict__ rpbW, const float* __restrict__ rpbS,
                                                  float* __restrict__ tab) {
    int bx = blockIdx.x;           // 0..71
    int shifted = bx >= 8;
    int idx = shifted ? bx - 8 : bx;
    int cls = shifted ? (idx >> 3) : 0;
    int head = idx & 7;
    const float* rpb = shifted ? rpbS : rpbW;
    float* out = tab + (size_t)bx * 4096;
    int i = threadIdx.x;
    int ih = i >> 4, iw = (i >> 2) & 3, it = i & 3;
    int mh = (cls >> 2) & 1, mw = (cls >> 1) & 1, mt = cls & 1;
    int labn = (mh ? (1 + (ih >> 1)) : 0) * 9 + (mw ? (1 + (iw >> 1)) : 0) * 3 + (mt ? (1 + (it >> 1)) : 0);
    for (int j = 0; j < 64; j++) {
        int jh = j >> 4, jw = (j >> 2) & 3, jt = j & 3;
        float v = rpb[(((ih - jh + 3) * 7 + (iw - jw + 3)) * 7 + (it - jt + 3)) * 8 + head];
        int labm = (mh ? (1 + (jh >> 1)) : 0) * 9 + (mw ? (1 + (jw >> 1)) : 0) * 3 + (mt ? (1 + (jt >> 1)) : 0);
        if (labm != labn) v -= 100.0f;
        out[i * 64 + j] = v;
    }
}

// ---------- LayerNorm (one wave per token) ----------
template<int GATHER, int F32OUT>
__global__ __launch_bounds__(256) void ln_kernel(const float* __restrict__ resid,
                                                 const float* __restrict__ g, const float* __restrict__ b,
                                                 void* __restrict__ outp, int shift) {
    int lane = threadIdx.x & 63;
    int row  = blockIdx.x * 4 + (threadIdx.x >> 6);
    int src  = GATHER ? map_token(row, shift) : row;
    float4 x = ((const float4*)(resid + src * 256))[lane];
    float s1 = x.x + x.y + x.z + x.w;
    float s2 = x.x * x.x + x.y * x.y + x.z * x.z + x.w * x.w;
    #pragma unroll
    for (int off = 1; off < 64; off <<= 1) { s1 += __shfl_xor(s1, off); s2 += __shfl_xor(s2, off); }
    float mean = s1 * (1.0f / 256.0f);
    float var  = s2 * (1.0f / 256.0f) - mean * mean;
    float rstd = rsqrtf(var + 1e-5f);
    int c = lane * 4;
    float4 gv = *(const float4*)(g + c);
    float4 bv = *(const float4*)(b + c);
    float y0 = (x.x - mean) * rstd * gv.x + bv.x;
    float y1 = (x.y - mean) * rstd * gv.y + bv.y;
    float y2 = (x.z - mean) * rstd * gv.z + bv.z;
    float y3 = (x.w - mean) * rstd * gv.w + bv.w;
    if (F32OUT) {
        float4 o; o.x = y0; o.y = y1; o.z = y2; o.w = y3;
        *(float4*)((float*)outp + row * 256 + c) = o;
    } else {
        uint2 o; o.x = pk(y0, y1); o.y = pk(y2, y3);
        *(uint2*)((u16*)outp + row * 256 + c) = o;
    }
}

// ---------- GEMM: C[M,N] = A[M,K] @ W[N,K]^T + bias ----------
// Block tile 256M x 128N, BK=32, 4 waves stacked along M; wave tile 64M x 128N
// (4 A-frags + 8 B-frags -> 32 MFMA per iter). C^T operand order for vector stores.
// EPI 0: bf16 store; 1: GELU + bf16 store; 2: resid += ; 3: resid[map_token] +=
template<int EPI>
__global__ __launch_bounds__(256, 2) void gemm4(const u16* __restrict__ A, const u16* __restrict__ W,
                                                const float* __restrict__ bias,
                                                u16* __restrict__ outb, float* __restrict__ resid,
                                                int Nout, int K, int shift) {
    __shared__ u16 As[256 * 32];
    __shared__ u16 Bs[128 * 32];
    int tid = threadIdx.x;
    int lane = tid & 63, w = tid >> 6;
    int m0 = blockIdx.x * 256, n0 = blockIdx.y * 128;
    int lr = lane & 15, q = lane >> 4;
    int sw = q ^ ((lr >> 1) & 3);          // conflict-free frag-read swizzle (measured 0 in r3)

    fx4 acc[4][8] = {};   // acc[i][j]: row = m0+w*64+i*16+lr, cols = n0+j*16+q*4+{0..3}

    for (int kt = 0; kt < K; kt += 32) {
        __syncthreads();
        #pragma unroll
        for (int s = 0; s < 4; s++) {
            int sl = s * 256 + tid;                 // 16B granule slot
            int row = sl >> 2;
            int kg = (sl & 3) ^ ((row >> 1) & 3);   // XOR-swizzled granule
            gl2lds16(A + (size_t)(m0 + row) * K + kt + kg * 8, As + sl * 8);
        }
        #pragma unroll
        for (int s = 0; s < 2; s++) {
            int sl = s * 256 + tid;
            int row = sl >> 2;
            int kg = (sl & 3) ^ ((row >> 1) & 3);
            gl2lds16(W + (size_t)(n0 + row) * K + kt + kg * 8, Bs + sl * 8);
        }
        __syncthreads();
        bfx8 bfr[8];
        #pragma unroll
        for (int j = 0; j < 8; j++)
            bfr[j] = *(const bfx8*)(Bs + ((j * 16 + lr) * 4 + sw) * 8);
        #pragma unroll
        for (int i = 0; i < 4; i++) {
            bfx8 af = *(const bfx8*)(As + ((w * 64 + i * 16 + lr) * 4 + sw) * 8);
            #pragma unroll
            for (int j = 0; j < 8; j++)
                acc[i][j] = __builtin_amdgcn_mfma_f32_16x16x32_bf16(bfr[j], af, acc[i][j], 0, 0, 0);
        }
    }

    float4 bv[8];
    #pragma unroll
    for (int j = 0; j < 8; j++) bv[j] = *(const float4*)(bias + n0 + j * 16 + q * 4);
    #pragma unroll
    for (int i = 0; i < 4; i++) {
        int gr = m0 + w * 64 + i * 16 + lr;
        int orow = (EPI == 3) ? map_token(gr, shift) : gr;
        #pragma unroll
        for (int j = 0; j < 8; j++) {
            int gc = n0 + j * 16 + q * 4;
            float v0 = acc[i][j][0] + bv[j].x;
            float v1 = acc[i][j][1] + bv[j].y;
            float v2 = acc[i][j][2] + bv[j].z;
            float v3 = acc[i][j][3] + bv[j].w;
            if (EPI == 0) {
                uint2 o; o.x = pk(v0, v1); o.y = pk(v2, v3);
                *(uint2*)(outb + (size_t)gr * Nout + gc) = o;
            } else if (EPI == 1) {
                uint2 o; o.x = pk(gelu(v0), gelu(v1)); o.y = pk(gelu(v2), gelu(v3));
                *(uint2*)(outb + (size_t)gr * Nout + gc) = o;
            } else {
                float4 rv = *(float4*)(resid + orow * 256 + gc);
                rv.x += v0; rv.y += v1; rv.z += v2; rv.w += v3;
                *(float4*)(resid + orow * 256 + gc) = rv;
            }
        }
    }
}

// ---------- MFMA attention: one wave per (window, head), 2 waves/block, table bias ----------
__global__ __launch_bounds__(128) void attn3(const u16* __restrict__ qkv, const float* __restrict__ tab,
                                             u16* __restrict__ outb, int masked) {
    __shared__ u16 Pl[2][64][72];
    __shared__ u16 VT[2][32][72];
    int w = threadIdx.x >> 6, lane = threadIdx.x & 63;
    int id = blockIdx.x * 2 + w;
    int win = id >> 3, head = id & 7;
    int lr = lane & 15, q = lane >> 4;
    const u16* base = qkv + (size_t)win * 64 * 768 + head * 32;

    bfx8 qf[4], kf[4];
    #pragma unroll
    for (int t = 0; t < 4; t++) {
        const u16* rq = base + (lr + 16 * t) * 768 + q * 8;
        qf[t] = *(const bfx8*)(rq);
        kf[t] = *(const bfx8*)(rq + 256);
    }
    {
        const u16* rv = base + lane * 768 + 512;
        #pragma unroll
        for (int c = 0; c < 32; c += 8) {
            bfx8 vv = *(const bfx8*)(rv + c);
            #pragma unroll
            for (int j = 0; j < 8; j++) VT[w][c + j][lane] = ((const u16*)&vv)[j];
        }
    }

    // S^T[j][i]: lane holds col i = lr+16it, regs rows j = q*4+r+16jt
    fx4 sT[4][4] = {};
    #pragma unroll
    for (int jt = 0; jt < 4; jt++)
        #pragma unroll
        for (int it = 0; it < 4; it++)
            sT[jt][it] = __builtin_amdgcn_mfma_f32_16x16x32_bf16(kf[jt], qf[it], sT[jt][it], 0, 0, 0);

    int wh = win >> 6, ww = (win >> 3) & 7, wt = win & 7;
    int slab = masked ? (8 + ((((wh == 7) ? 4 : 0) | ((ww == 7) ? 2 : 0) | ((wt == 7) ? 1 : 0)) * 8) + head)
                      : head;
    const float* bt = tab + (size_t)slab * 4096 + q * 4;
    const float scale = 0.17677669529663687f;

    #pragma unroll
    for (int it = 0; it < 4; it++) {
        int i = lr + 16 * it;
        const float* br = bt + i * 64;
        float sv[4][4];
        float mx = -1e30f;
        #pragma unroll
        for (int jt = 0; jt < 4; jt++) {
            float4 bb = *(const float4*)(br + 16 * jt);
            sv[jt][0] = sT[jt][it][0] * scale + bb.x;
            sv[jt][1] = sT[jt][it][1] * scale + bb.y;
            sv[jt][2] = sT[jt][it][2] * scale + bb.z;
            sv[jt][3] = sT[jt][it][3] * scale + bb.w;
            mx = fmaxf(mx, fmaxf(fmaxf(sv[jt][0], sv[jt][1]), fmaxf(sv[jt][2], sv[jt][3])));
        }
        mx = fmaxf(mx, __shfl_xor(mx, 16));
        mx = fmaxf(mx, __shfl_xor(mx, 32));
        float sum = 0.f;
        #pragma unroll
        for (int jt = 0; jt < 4; jt++)
            #pragma unroll
            for (int r = 0; r < 4; r++) { sv[jt][r] = __expf(sv[jt][r] - mx); sum += sv[jt][r]; }
        sum += __shfl_xor(sum, 16);
        sum += __shfl_xor(sum, 32);
        float inv = 1.0f / sum;
        #pragma unroll
        for (int jt = 0; jt < 4; jt++) {
            uint2 pw;
            pw.x = pk(sv[jt][0] * inv, sv[jt][1] * inv);
            pw.y = pk(sv[jt][2] * inv, sv[jt][3] * inv);
            *(uint2*)&Pl[w][i][q * 4 + 16 * jt] = pw;
        }
    }

    // O: lane holds row i = lr+16it, regs cols d = q*4+r+16dt
    fx4 o[4][2] = {};
    #pragma unroll
    for (int kk = 0; kk < 2; kk++) {
        bfx8 pf[4], vf[2];
        #pragma unroll
        for (int it = 0; it < 4; it++) pf[it] = *(const bfx8*)&Pl[w][lr + 16 * it][q * 8 + 32 * kk];
        #pragma unroll
        for (int dt = 0; dt < 2; dt++) vf[dt] = *(const bfx8*)&VT[w][lr + 16 * dt][q * 8 + 32 * kk];
        #pragma unroll
        for (int it = 0; it < 4; it++)
            #pragma unroll
            for (int dt = 0; dt < 2; dt++)
                o[it][dt] = __builtin_amdgcn_mfma_f32_16x16x32_bf16(vf[dt], pf[it], o[it][dt], 0, 0, 0);
    }

    u16* ob = outb + (size_t)win * 64 * 256 + head * 32;
    #pragma unroll
    for (int it = 0; it < 4; it++) {
        int i = lr + 16 * it;
        #pragma unroll
        for (int dt = 0; dt < 2; dt++) {
            uint2 ov;
            ov.x = pk(o[it][dt][0], o[it][dt][1]);
            ov.y = pk(o[it][dt][2], o[it][dt][3]);
            *(uint2*)(ob + i * 256 + dt * 16 + q * 4) = ov;
        }
    }
}

// ---------- [L,C] -> [C,L] fp32 transpose ----------
__global__ __launch_bounds__(256) void transpose_f32(const float* __restrict__ in, float* __restrict__ out) {
    __shared__ float tile[64][65];
    int t0 = blockIdx.x * 64;
    int c0 = blockIdx.y * 64;
    int row = threadIdx.x >> 2, cg = (threadIdx.x & 3) * 16;
    const float* src = in + (t0 + row) * 256 + c0 + cg;
    #pragma unroll
    for (int j = 0; j < 16; j += 4) {
        float4 v = *(const float4*)(src + j);
        tile[row][cg + j] = v.x; tile[row][cg + j + 1] = v.y;
        tile[row][cg + j + 2] = v.z; tile[row][cg + j + 3] = v.w;
    }
    __syncthreads();
    float tmp[16];
    #pragma unroll
    for (int j = 0; j < 16; j++) tmp[j] = tile[cg + j][row];
    float* dst = out + (c0 + row) * 32768 + t0 + cg;
    #pragma unroll
    for (int j = 0; j < 4; j++) *(float4*)(dst + 4 * j) = *(float4*)(tmp + 4 * j);
}

extern "C" void kernel_launch(void* const* d_in, const int* in_sizes, int n_in,
                              void* d_out, int out_size, void* d_ws, size_t ws_size,
                              hipStream_t stream) {
    const float* x      = (const float*)d_in[0];
    const float* norm_g = (const float*)d_in[4];
    const float* norm_b = (const float*)d_in[5];

    char* wsb = (char*)d_ws;
    float* resid = (float*)wsb;                                   // [0, 32MB)  fp32 residual
    u16*   xn    = (u16*)(wsb + (size_t)32 * 1024 * 1024);        // [32, 48MB) LN output (bf16)
    u16*   big   = (u16*)(wsb + (size_t)48 * 1024 * 1024);        // [48,112MB) qkv (48MB) / fc1 out (64MB)
    u16*   attnb = (u16*)(wsb + (size_t)96 * 1024 * 1024);        // [96,112MB) attn out (dead before fc1)
    u16*   wb    = (u16*)(wsb + (size_t)112 * 1024 * 1024);       // [112,115MB) bf16 weights
    float* tab   = (float*)(wsb + (size_t)115 * 1024 * 1024);     // [115,116.2MB) bias tables (72 slabs x 16KB)
    float* xnf   = (float*)(wsb + (size_t)48 * 1024 * 1024);      // final LN fp32 (big is dead)

    CvtArgs ca;
    static const int offs[9] = {0, 196608, 262144, 524288, 786432, 983040, 1048576, 1310720, 1572864};
    for (int i = 0; i < 9; i++) ca.cum[i] = offs[i];
    ca.src[0] = (const float*)d_in[6 + 2];   // wqkvw
    ca.src[1] = (const float*)d_in[6 + 5];   // wprojw
    ca.src[2] = (const float*)d_in[6 + 9];   // wfc1w
    ca.src[3] = (const float*)d_in[6 + 11];  // wfc2w
    ca.src[4] = (const float*)d_in[19 + 2];  // sqkvw
    ca.src[5] = (const float*)d_in[19 + 5];  // sprojw
    ca.src[6] = (const float*)d_in[19 + 9];  // sfc1w
    ca.src[7] = (const float*)d_in[19 + 11]; // sfc2w
    cvt_kernel<<<1536, 256, 0, stream>>>(ca, wb);
    bias_kernel<<<72, 64, 0, stream>>>((const float*)d_in[6 + 4], (const float*)d_in[19 + 4], tab);

    hipMemcpyAsync(resid, x, (size_t)32768 * 256 * 4, hipMemcpyDeviceToDevice, stream);

    for (int blk = 0; blk < 2; blk++) {
        void* const* P = d_in + 6 + blk * 13;
        const float* n1g  = (const float*)P[0];
        const float* n1b  = (const float*)P[1];
        const float* qkvb = (const float*)P[3];
        const float* pjb  = (const float*)P[6];
        const float* n2g  = (const float*)P[7];
        const float* n2b  = (const float*)P[8];
        const float* f1b  = (const float*)P[10];
        const float* f2b_ = (const float*)P[12];
        const u16* qkvw = wb + offs[0] + blk * 786432;
        const u16* pjw  = wb + offs[1] + blk * 786432;
        const u16* f1w  = wb + offs[2] + blk * 786432;
        const u16* f2w  = wb + offs[3] + blk * 786432;
        int shift = blk ? 2 : 0;

        ln_kernel<1, 0><<<8192, 256, 0, stream>>>(resid, n1g, n1b, xn, shift);
        gemm4<0><<<dim3(128, 6), 256, 0, stream>>>(xn, qkvw, qkvb, big, nullptr, 768, 256, 0);
        attn3<<<2048, 128, 0, stream>>>(big, tab, attnb, blk);
        gemm4<3><<<dim3(128, 2), 256, 0, stream>>>(attnb, pjw, pjb, nullptr, resid, 256, 256, shift);
        ln_kernel<0, 0><<<8192, 256, 0, stream>>>(resid, n2g, n2b, xn, 0);
        gemm4<1><<<dim3(128, 8), 256, 0, stream>>>(xn, f1w, f1b, big, nullptr, 1024, 256, 0);
        gemm4<2><<<dim3(128, 2), 256, 0, stream>>>(big, f2w, f2b_, nullptr, resid, 256, 1024, 0);
    }

    ln_kernel<0, 1><<<8192, 256, 0, stream>>>(resid, norm_g, norm_b, xnf, 0);
    transpose_f32<<<dim3(512, 4), 256, 0, stream>>>(xnf, (float*)d_out);
}

// Round 6
// 534.532 us; speedup vs baseline: 1.0481x; 1.0481x over previous
//
#include <hip/hip_runtime.h>

typedef unsigned short u16;
typedef unsigned int   u32;
typedef __bf16 bfx8 __attribute__((ext_vector_type(8)));
typedef float  fx4  __attribute__((ext_vector_type(4)));

__device__ __forceinline__ u16 f2b(float f) {
    union { float f; u32 i; } v; v.f = f;
    u32 r = (v.i + 0x7fffu + ((v.i >> 16) & 1u)) >> 16;
    return (u16)r;
}
__device__ __forceinline__ u32 pk(float a, float b) {
    return (u32)f2b(a) | ((u32)f2b(b) << 16);
}
__device__ __forceinline__ float gelu(float x) {
    float u = 0.7978845608028654f * x * (1.0f + 0.044715f * x * x);
    float e = __expf(2.0f * u);
    float t = 1.0f - 2.0f / (e + 1.0f);   // tanh(u)
    return 0.5f * x * (1.0f + t);
}

__device__ __forceinline__ void gl2lds16(const u16* g, u16* l) {
    __builtin_amdgcn_global_load_lds(
        (const __attribute__((address_space(1))) u32*)(const void*)g,
        (__attribute__((address_space(3))) u32*)(void*)l, 16, 0, 0);
}

// partitioned row r (window-major) -> token index in [0,32768), with roll shift
__device__ __forceinline__ int map_token(int r, int shift) {
    int win = r >> 6, n = r & 63;
    int wh = win >> 6, ww = (win >> 3) & 7, wt = win & 7;
    int h = wh * 4 + (n >> 4);
    int w = ww * 4 + ((n >> 2) & 3);
    int t = wt * 4 + (n & 3);
    h = (h + shift) & 31; w = (w + shift) & 31; t = (t + shift) & 31;
    return (h << 10) | (w << 5) | t;
}

// ---------- batched fp32 -> bf16 weight conversion ----------
struct CvtArgs { const float* src[8]; int cum[9]; };
__global__ __launch_bounds__(256) void cvt_kernel(CvtArgs a, u16* __restrict__ dst) {
    int g = (blockIdx.x * 256 + threadIdx.x) * 4;
    int t = 0;
    #pragma unroll
    for (int i = 1; i < 8; i++) t += (g >= a.cum[i]);
    int local = g - a.cum[t];
    float4 f = *(const float4*)(a.src[t] + local);
    uint2 o; o.x = pk(f.x, f.y); o.y = pk(f.z, f.w);
    *(uint2*)(dst + g) = o;
}

// ---------- attention bias+mask table: slab 0..7 = unshifted heads; 8+cls*8+head = shifted ----------
__global__ __launch_bounds__(64) void bias_kernel(const float* __restrict__ rpbW, const float* __restrict__ rpbS,
                                                  float* __restrict__ tab) {
    int bx = blockIdx.x;           // 0..71
    int shifted = bx >= 8;
    int idx = shifted ? bx - 8 : bx;
    int cls = shifted ? (idx >> 3) : 0;
    int head = idx & 7;
    const float* rpb = shifted ? rpbS : rpbW;
    float* out = tab + (size_t)bx * 4096;
    int i = threadIdx.x;
    int ih = i >> 4, iw = (i >> 2) & 3, it = i & 3;
    int mh = (cls >> 2) & 1, mw = (cls >> 1) & 1, mt = cls & 1;
    int labn = (mh ? (1 + (ih >> 1)) : 0) * 9 + (mw ? (1 + (iw >> 1)) : 0) * 3 + (mt ? (1 + (it >> 1)) : 0);
    for (int j = 0; j < 64; j++) {
        int jh = j >> 4, jw = (j >> 2) & 3, jt = j & 3;
        float v = rpb[(((ih - jh + 3) * 7 + (iw - jw + 3)) * 7 + (it - jt + 3)) * 8 + head];
        int labm = (mh ? (1 + (jh >> 1)) : 0) * 9 + (mw ? (1 + (jw >> 1)) : 0) * 3 + (mt ? (1 + (jt >> 1)) : 0);
        if (labm != labn) v -= 100.0f;
        out[i * 64 + j] = v;
    }
}

// ---------- LayerNorm (one wave per token) ----------
template<int GATHER, int F32OUT>
__global__ __launch_bounds__(256) void ln_kernel(const float* __restrict__ resid,
                                                 const float* __restrict__ g, const float* __restrict__ b,
                                                 void* __restrict__ outp, int shift) {
    int lane = threadIdx.x & 63;
    int row  = blockIdx.x * 4 + (threadIdx.x >> 6);
    int src  = GATHER ? map_token(row, shift) : row;
    float4 x = ((const float4*)(resid + src * 256))[lane];
    float s1 = x.x + x.y + x.z + x.w;
    float s2 = x.x * x.x + x.y * x.y + x.z * x.z + x.w * x.w;
    #pragma unroll
    for (int off = 1; off < 64; off <<= 1) { s1 += __shfl_xor(s1, off); s2 += __shfl_xor(s2, off); }
    float mean = s1 * (1.0f / 256.0f);
    float var  = s2 * (1.0f / 256.0f) - mean * mean;
    float rstd = rsqrtf(var + 1e-5f);
    int c = lane * 4;
    float4 gv = *(const float4*)(g + c);
    float4 bv = *(const float4*)(b + c);
    float y0 = (x.x - mean) * rstd * gv.x + bv.x;
    float y1 = (x.y - mean) * rstd * gv.y + bv.y;
    float y2 = (x.z - mean) * rstd * gv.z + bv.z;
    float y3 = (x.w - mean) * rstd * gv.w + bv.w;
    if (F32OUT) {
        float4 o; o.x = y0; o.y = y1; o.z = y2; o.w = y3;
        *(float4*)((float*)outp + row * 256 + c) = o;
    } else {
        uint2 o; o.x = pk(y0, y1); o.y = pk(y2, y3);
        *(uint2*)((u16*)outp + row * 256 + c) = o;
    }
}

// ---------- GEMM: C[M,N] = A[M,K] @ W[N,K]^T + bias ----------
// 128x128 block tile, BK=32, 4 waves (wave tile 64x64), loop-carried staging pointers.
// C^T operand order: lane holds output ROW (lr), regs hold 4 consecutive COLS (q*4+r).
// EPI 0: bf16 store; 1: GELU+bf16 store; 2: resid+=; 3: resid[map_token]+=; 4: resid[map_token]=x+v
template<int EPI>
__global__ __launch_bounds__(256) void gemm5(const u16* __restrict__ A, const u16* __restrict__ W,
                                             const float* __restrict__ bias,
                                             u16* __restrict__ outb, float* __restrict__ resid,
                                             const float* __restrict__ xin,
                                             int Nout, int K, int shift) {
    __shared__ u16 As[128 * 32];
    __shared__ u16 Bs[128 * 32];
    int tid = threadIdx.x;
    int lane = tid & 63, w = tid >> 6;
    int wm = w >> 1, wn = w & 1;
    int m0 = blockIdx.x * 128, n0 = blockIdx.y * 128;
    int lr = lane & 15, q = lane >> 4;
    int sw = q ^ ((lr >> 1) & 3);   // conflict-free frag-read swizzle (0 conflicts measured r3)

    // staging geometry: slot = s*256+tid (s=0,1); row = slot>>2; kg = (slot&3)^((row>>1)&3)
    int s0 = tid, s1 = 256 + tid;
    int r0 = s0 >> 2, r1 = s1 >> 2;
    int k0 = (s0 & 3) ^ ((r0 >> 1) & 3);
    int k1 = (s1 & 3) ^ ((r1 >> 1) & 3);
    const u16* ga0 = A + (size_t)(m0 + r0) * K + k0 * 8;
    const u16* ga1 = A + (size_t)(m0 + r1) * K + k1 * 8;
    const u16* gb0 = W + (size_t)(n0 + r0) * K + k0 * 8;
    const u16* gb1 = W + (size_t)(n0 + r1) * K + k1 * 8;
    u16* la0 = As + s0 * 8; u16* la1 = As + s1 * 8;
    u16* lb0 = Bs + s0 * 8; u16* lb1 = Bs + s1 * 8;

    // loop-invariant LDS read bases
    const u16* rdA = As + (wm * 64 + lr) * 32 + sw * 8;   // + t*512 per frag t
    const u16* rdB = Bs + (wn * 64 + lr) * 32 + sw * 8;

    fx4 acc[4][4] = {};   // acc[i][j]: row = m0+wm*64+i*16+lr, cols = n0+wn*64+j*16+q*4+{0..3}

    for (int kt = 0; kt < K; kt += 32) {
        __syncthreads();
        gl2lds16(ga0, la0); gl2lds16(ga1, la1);
        gl2lds16(gb0, lb0); gl2lds16(gb1, lb1);
        ga0 += 32; ga1 += 32; gb0 += 32; gb1 += 32;
        __syncthreads();
        bfx8 af[4], bfr[4];
        #pragma unroll
        for (int t = 0; t < 4; t++) {
            af[t]  = *(const bfx8*)(rdA + t * 512);
            bfr[t] = *(const bfx8*)(rdB + t * 512);
        }
        #pragma unroll
        for (int i = 0; i < 4; i++)
            #pragma unroll
            for (int j = 0; j < 4; j++)
                acc[i][j] = __builtin_amdgcn_mfma_f32_16x16x32_bf16(bfr[j], af[i], acc[i][j], 0, 0, 0);
    }

    float4 bv[4];
    #pragma unroll
    for (int j = 0; j < 4; j++) bv[j] = *(const float4*)(bias + n0 + wn * 64 + j * 16 + q * 4);
    #pragma unroll
    for (int i = 0; i < 4; i++) {
        int gr = m0 + wm * 64 + i * 16 + lr;
        int orow = (EPI >= 3) ? map_token(gr, shift) : gr;
        #pragma unroll
        for (int j = 0; j < 4; j++) {
            int gc = n0 + wn * 64 + j * 16 + q * 4;
            float v0 = acc[i][j][0] + bv[j].x;
            float v1 = acc[i][j][1] + bv[j].y;
            float v2 = acc[i][j][2] + bv[j].z;
            float v3 = acc[i][j][3] + bv[j].w;
            if (EPI == 0) {
                uint2 o; o.x = pk(v0, v1); o.y = pk(v2, v3);
                *(uint2*)(outb + (size_t)gr * Nout + gc) = o;
            } else if (EPI == 1) {
                uint2 o; o.x = pk(gelu(v0), gelu(v1)); o.y = pk(gelu(v2), gelu(v3));
                *(uint2*)(outb + (size_t)gr * Nout + gc) = o;
            } else if (EPI == 4) {
                float4 xv = *(const float4*)(xin + orow * 256 + gc);
                float4 rv;
                rv.x = xv.x + v0; rv.y = xv.y + v1; rv.z = xv.z + v2; rv.w = xv.w + v3;
                *(float4*)(resid + orow * 256 + gc) = rv;
            } else {
                float4 rv = *(float4*)(resid + orow * 256 + gc);
                rv.x += v0; rv.y += v1; rv.z += v2; rv.w += v3;
                *(float4*)(resid + orow * 256 + gc) = rv;
            }
        }
    }
}

// ---------- MFMA attention: one wave per (window, head), 2 waves/block, table bias ----------
__global__ __launch_bounds__(128) void attn3(const u16* __restrict__ qkv, const float* __restrict__ tab,
                                             u16* __restrict__ outb, int masked) {
    __shared__ u16 Pl[2][64][72];
    __shared__ u16 VT[2][32][72];
    int w = threadIdx.x >> 6, lane = threadIdx.x & 63;
    int id = blockIdx.x * 2 + w;
    int win = id >> 3, head = id & 7;
    int lr = lane & 15, q = lane >> 4;
    const u16* base = qkv + (size_t)win * 64 * 768 + head * 32;

    bfx8 qf[4], kf[4];
    #pragma unroll
    for (int t = 0; t < 4; t++) {
        const u16* rq = base + (lr + 16 * t) * 768 + q * 8;
        qf[t] = *(const bfx8*)(rq);
        kf[t] = *(const bfx8*)(rq + 256);
    }
    {
        const u16* rv = base + lane * 768 + 512;
        #pragma unroll
        for (int c = 0; c < 32; c += 8) {
            bfx8 vv = *(const bfx8*)(rv + c);
            #pragma unroll
            for (int j = 0; j < 8; j++) VT[w][c + j][lane] = ((const u16*)&vv)[j];
        }
    }

    // S^T[j][i]: lane holds col i = lr+16it, regs rows j = q*4+r+16jt
    fx4 sT[4][4] = {};
    #pragma unroll
    for (int jt = 0; jt < 4; jt++)
        #pragma unroll
        for (int it = 0; it < 4; it++)
            sT[jt][it] = __builtin_amdgcn_mfma_f32_16x16x32_bf16(kf[jt], qf[it], sT[jt][it], 0, 0, 0);

    int wh = win >> 6, ww = (win >> 3) & 7, wt = win & 7;
    int slab = masked ? (8 + ((((wh == 7) ? 4 : 0) | ((ww == 7) ? 2 : 0) | ((wt == 7) ? 1 : 0)) * 8) + head)
                      : head;
    const float* bt = tab + (size_t)slab * 4096 + q * 4;
    const float scale = 0.17677669529663687f;

    #pragma unroll
    for (int it = 0; it < 4; it++) {
        int i = lr + 16 * it;
        const float* br = bt + i * 64;
        float sv[4][4];
        float mx = -1e30f;
        #pragma unroll
        for (int jt = 0; jt < 4; jt++) {
            float4 bb = *(const float4*)(br + 16 * jt);
            sv[jt][0] = sT[jt][it][0] * scale + bb.x;
            sv[jt][1] = sT[jt][it][1] * scale + bb.y;
            sv[jt][2] = sT[jt][it][2] * scale + bb.z;
            sv[jt][3] = sT[jt][it][3] * scale + bb.w;
            mx = fmaxf(mx, fmaxf(fmaxf(sv[jt][0], sv[jt][1]), fmaxf(sv[jt][2], sv[jt][3])));
        }
        mx = fmaxf(mx, __shfl_xor(mx, 16));
        mx = fmaxf(mx, __shfl_xor(mx, 32));
        float sum = 0.f;
        #pragma unroll
        for (int jt = 0; jt < 4; jt++)
            #pragma unroll
            for (int r = 0; r < 4; r++) { sv[jt][r] = __expf(sv[jt][r] - mx); sum += sv[jt][r]; }
        sum += __shfl_xor(sum, 16);
        sum += __shfl_xor(sum, 32);
        float inv = 1.0f / sum;
        #pragma unroll
        for (int jt = 0; jt < 4; jt++) {
            uint2 pw;
            pw.x = pk(sv[jt][0] * inv, sv[jt][1] * inv);
            pw.y = pk(sv[jt][2] * inv, sv[jt][3] * inv);
            *(uint2*)&Pl[w][i][q * 4 + 16 * jt] = pw;
        }
    }

    // O: lane holds row i = lr+16it, regs cols d = q*4+r+16dt
    fx4 o[4][2] = {};
    #pragma unroll
    for (int kk = 0; kk < 2; kk++) {
        bfx8 pf[4], vf[2];
        #pragma unroll
        for (int it = 0; it < 4; it++) pf[it] = *(const bfx8*)&Pl[w][lr + 16 * it][q * 8 + 32 * kk];
        #pragma unroll
        for (int dt = 0; dt < 2; dt++) vf[dt] = *(const bfx8*)&VT[w][lr + 16 * dt][q * 8 + 32 * kk];
        #pragma unroll
        for (int it = 0; it < 4; it++)
            #pragma unroll
            for (int dt = 0; dt < 2; dt++)
                o[it][dt] = __builtin_amdgcn_mfma_f32_16x16x32_bf16(vf[dt], pf[it], o[it][dt], 0, 0, 0);
    }

    u16* ob = outb + (size_t)win * 64 * 256 + head * 32;
    #pragma unroll
    for (int it = 0; it < 4; it++) {
        int i = lr + 16 * it;
        #pragma unroll
        for (int dt = 0; dt < 2; dt++) {
            uint2 ov;
            ov.x = pk(o[it][dt][0], o[it][dt][1]);
            ov.y = pk(o[it][dt][2], o[it][dt][3]);
            *(uint2*)(ob + i * 256 + dt * 16 + q * 4) = ov;
        }
    }
}

// ---------- [L,C] -> [C,L] fp32 transpose ----------
__global__ __launch_bounds__(256) void transpose_f32(const float* __restrict__ in, float* __restrict__ out) {
    __shared__ float tile[64][65];
    int t0 = blockIdx.x * 64;
    int c0 = blockIdx.y * 64;
    int row = threadIdx.x >> 2, cg = (threadIdx.x & 3) * 16;
    const float* src = in + (t0 + row) * 256 + c0 + cg;
    #pragma unroll
    for (int j = 0; j < 16; j += 4) {
        float4 v = *(const float4*)(src + j);
        tile[row][cg + j] = v.x; tile[row][cg + j + 1] = v.y;
        tile[row][cg + j + 2] = v.z; tile[row][cg + j + 3] = v.w;
    }
    __syncthreads();
    float tmp[16];
    #pragma unroll
    for (int j = 0; j < 16; j++) tmp[j] = tile[cg + j][row];
    float* dst = out + (c0 + row) * 32768 + t0 + cg;
    #pragma unroll
    for (int j = 0; j < 4; j++) *(float4*)(dst + 4 * j) = *(float4*)(tmp + 4 * j);
}

extern "C" void kernel_launch(void* const* d_in, const int* in_sizes, int n_in,
                              void* d_out, int out_size, void* d_ws, size_t ws_size,
                              hipStream_t stream) {
    const float* x      = (const float*)d_in[0];
    const float* norm_g = (const float*)d_in[4];
    const float* norm_b = (const float*)d_in[5];

    char* wsb = (char*)d_ws;
    float* resid = (float*)wsb;                                   // [0, 32MB)  fp32 residual
    u16*   xn    = (u16*)(wsb + (size_t)32 * 1024 * 1024);        // [32, 48MB) LN output (bf16)
    u16*   big   = (u16*)(wsb + (size_t)48 * 1024 * 1024);        // [48,112MB) qkv (48MB) / fc1 out (64MB)
    u16*   attnb = (u16*)(wsb + (size_t)96 * 1024 * 1024);        // [96,112MB) attn out (dead before fc1)
    u16*   wb    = (u16*)(wsb + (size_t)112 * 1024 * 1024);       // [112,115MB) bf16 weights
    float* tab   = (float*)(wsb + (size_t)115 * 1024 * 1024);     // [115,116.2MB) bias tables
    float* xnf   = (float*)(wsb + (size_t)48 * 1024 * 1024);      // final LN fp32 (big is dead)

    CvtArgs ca;
    static const int offs[9] = {0, 196608, 262144, 524288, 786432, 983040, 1048576, 1310720, 1572864};
    for (int i = 0; i < 9; i++) ca.cum[i] = offs[i];
    ca.src[0] = (const float*)d_in[6 + 2];   // wqkvw
    ca.src[1] = (const float*)d_in[6 + 5];   // wprojw
    ca.src[2] = (const float*)d_in[6 + 9];   // wfc1w
    ca.src[3] = (const float*)d_in[6 + 11];  // wfc2w
    ca.src[4] = (const float*)d_in[19 + 2];  // sqkvw
    ca.src[5] = (const float*)d_in[19 + 5];  // sprojw
    ca.src[6] = (const float*)d_in[19 + 9];  // sfc1w
    ca.src[7] = (const float*)d_in[19 + 11]; // sfc2w
    cvt_kernel<<<1536, 256, 0, stream>>>(ca, wb);
    bias_kernel<<<72, 64, 0, stream>>>((const float*)d_in[6 + 4], (const float*)d_in[19 + 4], tab);

    for (int blk = 0; blk < 2; blk++) {
        void* const* P = d_in + 6 + blk * 13;
        const float* n1g  = (const float*)P[0];
        const float* n1b  = (const float*)P[1];
        const float* qkvb = (const float*)P[3];
        const float* pjb  = (const float*)P[6];
        const float* n2g  = (const float*)P[7];
        const float* n2b  = (const float*)P[8];
        const float* f1b  = (const float*)P[10];
        const float* f2b_ = (const float*)P[12];
        const u16* qkvw = wb + offs[0] + blk * 786432;
        const u16* pjw  = wb + offs[1] + blk * 786432;
        const u16* f1w  = wb + offs[2] + blk * 786432;
        const u16* f2w  = wb + offs[3] + blk * 786432;
        int shift = blk ? 2 : 0;
        const float* ln1src = blk ? resid : x;   // blk0: resid not yet initialized; read x

        ln_kernel<1, 0><<<8192, 256, 0, stream>>>(ln1src, n1g, n1b, xn, shift);
        gemm5<0><<<dim3(256, 6), 256, 0, stream>>>(xn, qkvw, qkvb, big, nullptr, nullptr, 768, 256, 0);
        attn3<<<2048, 128, 0, stream>>>(big, tab, attnb, blk);
        if (blk == 0)
            gemm5<4><<<dim3(256, 2), 256, 0, stream>>>(attnb, pjw, pjb, nullptr, resid, x, 256, 256, 0);
        else
            gemm5<3><<<dim3(256, 2), 256, 0, stream>>>(attnb, pjw, pjb, nullptr, resid, nullptr, 256, 256, shift);
        ln_kernel<0, 0><<<8192, 256, 0, stream>>>(resid, n2g, n2b, xn, 0);
        gemm5<1><<<dim3(256, 8), 256, 0, stream>>>(xn, f1w, f1b, big, nullptr, nullptr, 1024, 256, 0);
        gemm5<2><<<dim3(256, 2), 256, 0, stream>>>(big, f2w, f2b_, nullptr, resid, nullptr, 256, 1024, 0);
    }

    ln_kernel<0, 1><<<8192, 256, 0, stream>>>(resid, norm_g, norm_b, xnf, 0);
    transpose_f32<<<dim3(512, 4), 256, 0, stream>>>(xnf, (float*)d_out);
}